// Round 2
// baseline (145.374 us; speedup 1.0000x reference)
//
#include <hip/hip_runtime.h>

// Soft-DTW (gamma=0.1) with normalization, batch 64, len 256, dim 8.
// W-space: W = -R/(gamma*ln2); recurrence W = D*K1 + m + log2(sum 2^(Wi-m)).
static constexpr float K1   = -14.426950408889634074f;   // -1/(gamma*ln2)
static constexpr float KOUT = -0.069314718055994530942f; // -gamma*ln2  (R = KOUT*W)
static constexpr float WBIG = -1.0e30f;                  // boundary (-inf surrogate)

__global__ void sdtw_zero(float* out) { out[0] = 0.0f; }

__global__ void __launch_bounds__(64, 1)
sdtw_kernel(const float* __restrict__ x, const float* __restrict__ y,
            float* __restrict__ out)
{
    const int batch = blockIdx.x;
    const int pair  = blockIdx.y;   // 0: xy, 1: xx, 2: yy
    const int lane  = threadIdx.x;  // 64 lanes, lane owns cols 4*lane..4*lane+3

    const float* A  = (pair == 2 ? y : x) + batch * 2048;  // rows side
    const float* Bp = (pair == 1 ? x : y) + batch * 2048;  // cols side

    __shared__ float xT[8][256];   // transposed A: conflict-free lane reads
    __shared__ float nxs[256];     // |x_i|^2

    #pragma unroll
    for (int rr = 0; rr < 4; ++rr) {
        int r = lane + rr * 64;
        float4 a0 = *reinterpret_cast<const float4*>(A + r * 8);
        float4 a1 = *reinterpret_cast<const float4*>(A + r * 8 + 4);
        xT[0][r] = a0.x; xT[1][r] = a0.y; xT[2][r] = a0.z; xT[3][r] = a0.w;
        xT[4][r] = a1.x; xT[5][r] = a1.y; xT[6][r] = a1.z; xT[7][r] = a1.w;
        nxs[r] = a0.x*a0.x + a0.y*a0.y + a0.z*a0.z + a0.w*a0.w
               + a1.x*a1.x + a1.y*a1.y + a1.z*a1.z + a1.w*a1.w;
    }

    // y-side: 4 columns x 8 dims in registers
    float b[4][8], nb[4];
    #pragma unroll
    for (int cc = 0; cc < 4; ++cc) {
        const float* bp = Bp + (4 * lane + cc) * 8;
        float4 b0 = *reinterpret_cast<const float4*>(bp);
        float4 b1 = *reinterpret_cast<const float4*>(bp + 4);
        b[cc][0]=b0.x; b[cc][1]=b0.y; b[cc][2]=b0.z; b[cc][3]=b0.w;
        b[cc][4]=b1.x; b[cc][5]=b1.y; b[cc][6]=b1.z; b[cc][7]=b1.w;
        nb[cc] = b0.x*b0.x + b0.y*b0.y + b0.z*b0.z + b0.w*b0.w
               + b1.x*b1.x + b1.y*b1.y + b1.z*b1.z + b1.w*b1.w;
    }

    __syncthreads();

    float up[4];                       // W[i-1][4l+cc] (own previous row)
    up[0]=up[1]=up[2]=up[3] = WBIG;
    float own_last  = WBIG;            // own last-col result of most recent row
    float left_prev = WBIG;            // neighbor's last-col from two steps ago
    float xcur[8], nxcur;
    #pragma unroll
    for (int d = 0; d < 8; ++d) xcur[d] = xT[d][0];
    nxcur = nxs[0];

    for (int s = 0; s < 319; ++s) {
        const int i = s - lane;        // row this lane processes this step

        // prefetch next row (off critical chain)
        int ipf = s + 1 - lane;
        ipf = ipf < 0 ? 0 : (ipf > 255 ? 255 : ipf);
        float xn[8], nxn;
        #pragma unroll
        for (int d = 0; d < 8; ++d) xn[d] = xT[d][ipf];
        nxn = nxs[ipf];

        // neighbor exchange (all lanes execute the shfl)
        float lin  = __shfl_up(own_last, 1); // lane l-1 last-col, step s-1 -> left
        float ulin = left_prev;              // lane l-1 last-col, step s-2 -> upleft
        left_prev  = lin;
        if (lane == 0) { lin = WBIG; ulin = (s == 0) ? 0.0f : WBIG; }

        if (i >= 0 && i < 256) {
            float ulcur = ulin;
            if (i == 0) {
                up[0]=up[1]=up[2]=up[3] = WBIG;       // row -1 boundary
                if (lane != 0) ulcur = WBIG;           // upleft of col 4l at row 0
            }
            // distances for 4 cells (independent FMAs, overlap softmin chain)
            float Dw[4];
            #pragma unroll
            for (int cc = 0; cc < 4; ++cc) {
                float acc = xcur[0] * b[cc][0];
                #pragma unroll
                for (int d = 1; d < 8; ++d) acc = fmaf(xcur[d], b[cc][d], acc);
                Dw[cc] = fmaf(-2.0f, acc, nxcur + nb[cc]) * K1;
            }
            // 4 serial cells (left dependency)
            float lft = lin;
            #pragma unroll
            for (int cc = 0; cc < 4; ++cc) {
                float u  = up[cc];
                float ul = ulcur;
                float m  = fmaxf(fmaxf(u, ul), lft);
                float sum = __builtin_amdgcn_exp2f(u  - m)
                          + __builtin_amdgcn_exp2f(ul - m)
                          + __builtin_amdgcn_exp2f(lft - m);
                float w = Dw[cc] + m + __builtin_amdgcn_logf(sum);
                ulcur  = u;      // old up becomes next cell's upleft
                up[cc] = w;
                lft    = w;
            }
            own_last = lft;
        }

        #pragma unroll
        for (int d = 0; d < 8; ++d) xcur[d] = xn[d];
        nxcur = nxn;
    }

    if (lane == 63) {
        float r   = own_last * KOUT;                       // back to R-space
        float wgt = (pair == 0) ? (1.0f / 64.0f) : (-0.5f / 64.0f);
        atomicAdd(out, r * wgt);
    }
}

extern "C" void kernel_launch(void* const* d_in, const int* in_sizes, int n_in,
                              void* d_out, int out_size, void* d_ws, size_t ws_size,
                              hipStream_t stream)
{
    const float* x = (const float*)d_in[0];
    const float* y = (const float*)d_in[1];
    float* out = (float*)d_out;

    hipLaunchKernelGGL(sdtw_zero, dim3(1), dim3(1), 0, stream, out);
    hipLaunchKernelGGL(sdtw_kernel, dim3(64, 3), dim3(64), 0, stream, x, y, out);
}